// Round 12
// baseline (487.756 us; speedup 1.0000x reference)
//
#include <hip/hip_runtime.h>
#include <cmath>

// WaterNet: NH=128, NG=32, NR=15, NT=730, NS=800
#define NHID 128
#define NSITE 800
#define NTIME 730
#define NRTAP 15
constexpr int NSH = NSITE * NHID;  // 102400

typedef _Float16 f16x8 __attribute__((ext_vector_type(8)));
typedef float f32x4 __attribute__((ext_vector_type(4)));

__device__ __forceinline__ float tanh_fast(float x) {
    float e = __expf(2.0f * x);
    return 1.0f - 2.0f / (e + 1.0f);
}
__device__ __forceinline__ float sigmoid_fast(float x) {
    return 1.0f / (1.0f + __expf(-x));
}
__device__ __forceinline__ unsigned short h_bits(_Float16 h) {
    union { _Float16 h; unsigned short u; } c; c.h = h; return c.u;
}
__device__ __forceinline__ float h_val(unsigned short u) {
    union { unsigned short u; _Float16 h; } c; c.u = u; return (float)c.h;
}
// Swizzled index into 64-row A-fragment LDS tile: jg = k-octet (0..31), r = row (0..63).
// Conflict-free for L1 write and MFMA read (verified r7/r11: SQ_LDS_BANK_CONFLICT = 0).
__device__ __forceinline__ int ah_swz(int jg, int r) {
    return jg * 64 + ((r & ~7) | ((r ^ jg) & 7));
}

// ---------------------------------------------------------------------------
// P0: fcT2_w (fp32 [256][384]) -> fp16 MFMA layout w2s[K0][kg][col][e]
// ---------------------------------------------------------------------------
__global__ void k_prep_w2h(const float* __restrict__ w2, _Float16* __restrict__ w2s)
{
    int idx = blockIdx.x * 256 + threadIdx.x;
    if (idx >= 98304) return;
    int k = idx / 384, col = idx - k * 384;
    int K0 = k >> 5, kg = (k >> 3) & 3, e = k & 7;
    w2s[(size_t)K0 * 12288 + kg * 3072 + col * 8 + e] = (_Float16)w2[(size_t)k * 384 + col];
}

// ---------------------------------------------------------------------------
// A1: per-site layer-1 for all three heads.
// ---------------------------------------------------------------------------
__global__ void k_site_l1(const float* __restrict__ xc,
                          const float* __restrict__ w1W, const float* __restrict__ b1W,
                          const float* __restrict__ w1R, const float* __restrict__ b1R,
                          const float* __restrict__ w1T, const float* __restrict__ b1T,
                          float* __restrict__ h1w, float* __restrict__ h1r,
                          float* __restrict__ basec)
{
    __shared__ float xr[32];
    int s = blockIdx.x, j = threadIdx.x;
    if (j < 32) xr[j] = xc[s * 32 + j];
    __syncthreads();
    float aW = b1W[j], aR = b1R[j], aT = b1T[j];
#pragma unroll 8
    for (int k = 0; k < 32; ++k) {
        float xv = xr[k];
        aW = fmaf(xv, w1W[k * 256 + j], aW);
        aR = fmaf(xv, w1R[k * 256 + j], aR);
        aT = fmaf(xv, w1T[(6 + k) * 256 + j], aT);
    }
    h1w[s * 256 + j]   = tanh_fast(aW);
    h1r[s * 256 + j]   = tanh_fast(aR);
    basec[s * 256 + j] = aT;
}

// ---------------------------------------------------------------------------
// A2: static parameter head layer-2 + activations.
// ---------------------------------------------------------------------------
__global__ void k_whead(const float* __restrict__ h1w,
                        const float* __restrict__ w2, const float* __restrict__ b2,
                        float* __restrict__ params)
{
    __shared__ float h[8 * 256];
    int sBase = blockIdx.x * 8, g = blockIdx.y, tid = threadIdx.x;
    for (int p = tid; p < 2048; p += 128) h[p] = h1w[sBase * 256 + p];
    __syncthreads();
    float bias = b2[g * 128 + tid];
    float acc[8];
#pragma unroll
    for (int i = 0; i < 8; ++i) acc[i] = bias;
    for (int k = 0; k < 256; ++k) {
        float wv = w2[k * 896 + g * 128 + tid];
#pragma unroll
        for (int i = 0; i < 8; ++i) acc[i] = fmaf(h[i * 256 + k], wv, acc[i]);
    }
#pragma unroll
    for (int i = 0; i < 8; ++i) {
        float v = acc[i], o;
        if (g == 0 || g == 1 || g == 3)  o = sigmoid_fast(v);
        else if (g == 2)                 o = sigmoid_fast(v) * 0.1f;
        else if (g == 4)                 o = __expf(v) * 2.0f;
        else if (g == 5)                 o = fmaxf(v, 0.0f);
        else                             o = v;
        params[g * NSH + (sBase + i) * 128 + tid] = o;
    }
}

// ---------------------------------------------------------------------------
// A3: softmax of ga over 128 buckets, in place.
// ---------------------------------------------------------------------------
__global__ void k_softmax_ga(float* __restrict__ ga)
{
    int s = blockIdx.x, h = threadIdx.x;
    float v = ga[s * 128 + h];
    float m = v;
#pragma unroll
    for (int off = 32; off; off >>= 1) m = fmaxf(m, __shfl_xor(m, off));
    __shared__ float ra[2], rb[2];
    if ((h & 63) == 0) ra[h >> 6] = m;
    __syncthreads();
    m = fmaxf(ra[0], ra[1]);
    float e = __expf(v - m);
    float t = e;
#pragma unroll
    for (int off = 32; off; off >>= 1) t += __shfl_xor(t, off);
    if ((h & 63) == 0) rb[h >> 6] = t;
    __syncthreads();
    ga[s * 128 + h] = e / (rb[0] + rb[1]);
}

// ---------------------------------------------------------------------------
// A4: routing head layer-2, relu, [NRTAP][NSITE*NHID]
// ---------------------------------------------------------------------------
__global__ void k_rhead(const float* __restrict__ h1r,
                        const float* __restrict__ w2, const float* __restrict__ b2,
                        float* __restrict__ rbuf)
{
    __shared__ float h[8 * 256];
    int sBase = blockIdx.x * 8, g = blockIdx.y, tid = threadIdx.x;
    for (int p = tid; p < 2048; p += 128) h[p] = h1r[sBase * 256 + p];
    __syncthreads();
    int c = g * 128 + tid;
    float bias = b2[c];
    float acc[8];
#pragma unroll
    for (int i = 0; i < 8; ++i) acc[i] = bias;
    for (int k = 0; k < 256; ++k) {
        float wv = w2[k * 1920 + c];
#pragma unroll
        for (int i = 0; i < 8; ++i) acc[i] = fmaf(h[i * 256 + k], wv, acc[i]);
    }
    int hh = c / 15, ii = c - hh * 15;
#pragma unroll
    for (int i = 0; i < 8; ++i)
        rbuf[ii * NSH + (sBase + i) * 128 + hh] = fmaxf(acc[i], 0.0f);
}

// ---------------------------------------------------------------------------
// COMBO5: 512-thread blocks.
//   blocks [0,nScan): barrier-free scan of chunk c-1 (4 sites/block);
//   blocks [nScan,..): timehead 64-row tiles of chunk c. 8 waves; wave w
//   owns hidden cols w*16..+15 for ALL 3 channels x ALL 64 rows (mf=4) ->
//   3 B-loads/row (half of r11), same-lane pl/ev/vm -> one packed uint2
//   (8 B) store per cell. 2 barriers, 34.3 KB LDS.
// ---------------------------------------------------------------------------
struct ThSm3 {
    f16x8 Ah[2048];                 // 32 KB swizzled A fragments (64 rows)
    float xt[64][6];
    float pls[64], evs[64], psv[64];
};                                  // 35,072 B

__global__ __launch_bounds__(512, 2) void k_combo5(
    const float* __restrict__ x, const float* __restrict__ w1T,
    const float* __restrict__ basec, const f16x8* __restrict__ w2B,
    const float* __restrict__ b2,
    const float* __restrict__ params, const float* __restrict__ rbuf,
    float* __restrict__ state, float* __restrict__ fut, float* __restrict__ out,
    uint2* __restrict__ PVw, float* __restrict__ PSw, int t0h, int rowsH,
    const uint2* __restrict__ PVr, const float* __restrict__ PSr,
    int t0s, int Tcs, int isFirst, int nScan)
{
    __shared__ __align__(16) char smem[sizeof(ThSm3)];
    int tid = threadIdx.x;

    if ((int)blockIdx.x < nScan) {
        // ===================== SCAN (chunk c-1), 4 sites =====================
        float* part = (float*)smem;                 // [8][128] = 4 KB
        int sl = tid >> 7, hc = tid & 127;
        int lane = tid & 63, wid = tid >> 6;
        int site = blockIdx.x * 4 + sl;
        int cell = site * 128 + hc;

        float kp  = params[0 * NSH + cell];
        float ksP = params[1 * NSH + cell];
        float kgP = params[2 * NSH + cell];
        float gp  = params[3 * NSH + cell];
        float gL  = params[4 * NSH + cell];
        float qb  = params[5 * NSH + cell];
        float ga  = params[6 * NSH + cell];
        float kq  = ksP * (1.0f - gp);

        float wr[NRTAP];
#pragma unroll
        for (int i = 0; i < NRTAP; ++i) wr[i] = ga * rbuf[i * NSH + cell];

        float Sf, Ss, Sg, f[NRTAP];
        if (isFirst) {
            Sf = Ss = Sg = 0.0f;
#pragma unroll
            for (int i = 0; i < NRTAP; ++i) f[i] = 0.0f;
        } else {
            Sf = state[cell];
            Ss = state[NSH + cell];
            Sg = state[2 * NSH + cell];
#pragma unroll
            for (int i = 0; i < NRTAP; ++i) f[i] = fut[i * NSH + cell];
        }

        const uint2* pvp = PVr + cell;
        const uint2 zz = make_uint2(0u, 0u);

#define LD_T(PV_, PS_, T_) { int t_ = (T_); bool ok_ = t_ < Tcs;               \
        PV_ = ok_ ? pvp[(size_t)t_ * NSH] : zz;                                \
        PS_ = ok_ ? PSr[(size_t)t_ * 800 + site] : 0.0f; }

        uint2 pvA[4], pvB[4], pvC[4], pvD[4];
        float psA[4], psB[4], psC[4], psD[4];
#pragma unroll
        for (int i = 0; i < 4; ++i) LD_T(pvA[i], psA[i], i)
#pragma unroll
        for (int i = 0; i < 4; ++i) LD_T(pvB[i], psB[i], 4 + i)
#pragma unroll
        for (int i = 0; i < 4; ++i) LD_T(pvC[i], psC[i], 8 + i)
#pragma unroll
        for (int i = 0; i < 4; ++i) LD_T(pvD[i], psD[i], 12 + i)

        int ngroups = (Tcs + 3) >> 2;
        for (int g = 0; g < ngroups; ++g) {
            int tb = g * 4;
            uint2 pvE[4]; float psE[4];
#pragma unroll
            for (int i = 0; i < 4; ++i) LD_T(pvE[i], psE[i], tb + 16 + i)

            float cs[4];
#pragma unroll
            for (int i = 0; i < 4; ++i) {
                cs[i] = 0.0f;
                if (tb + i < Tcs) {
                    float pl = h_val((unsigned short)(pvA[i].x & 0xffffu));
                    float ev = h_val((unsigned short)(pvA[i].x >> 16));
                    float vm = h_val((unsigned short)(pvA[i].y & 0xffffu));
                    float ps = psA[i];

                    float x1 = Sf + ps;
                    float qf = fminf(x1, vm);
                    Sf = fmaxf(x1 - vm, 0.0f);
                    float H  = fmaxf(Ss + pl + qf - ev, 0.0f);
                    float qp = fmaxf(kp * (H - gL), 0.0f);
                    float mh = fminf(H, gL);
                    float qs = ksP * mh;
                    Ss = H - qp - qs;
                    float qg = fmaf(kgP, fmaf(qs, gp, Sg), qb);
                    Sg = Sg - qg;
                    float qt = qp + kq * mh + qg;
#pragma unroll
                    for (int j = 0; j < NRTAP; ++j) f[j] = fmaf(wr[j], qt, f[j]);
                    cs[i] = f[0];
#pragma unroll
                    for (int j = 0; j < NRTAP - 1; ++j) f[j] = f[j + 1];
                    f[NRTAP - 1] = 0.0f;
                }
            }
#pragma unroll
            for (int i = 0; i < 4; ++i) {
                float c = cs[i];
#pragma unroll
                for (int off = 32; off; off >>= 1) c += __shfl_xor(c, off);
                cs[i] = c;
            }
            if (lane == 0) {
#pragma unroll
                for (int i = 0; i < 4; ++i)
                    if (tb + i < Tcs) part[wid * 128 + tb + i] = cs[i];
            }
#pragma unroll
            for (int i = 0; i < 4; ++i) {
                pvA[i] = pvB[i]; pvB[i] = pvC[i]; pvC[i] = pvD[i]; pvD[i] = pvE[i];
                psA[i] = psB[i]; psB[i] = psC[i]; psC[i] = psD[i]; psD[i] = psE[i];
            }
        }
#undef LD_T

        state[cell]           = Sf;
        state[NSH + cell]     = Ss;
        state[2 * NSH + cell] = Sg;
#pragma unroll
        for (int i = 0; i < NRTAP; ++i) fut[i * NSH + cell] = f[i];

        __syncthreads();
        {
            int sl2 = tid >> 7, tl = tid & 127;
            for (int t = tl; t < Tcs; t += 128)
                out[(size_t)(t0s + t) * 800 + blockIdx.x * 4 + sl2] =
                    part[(sl2 * 2) * 128 + t] + part[(sl2 * 2 + 1) * 128 + t];
        }
        return;
    }

    // ===================== TIMEHEAD tile (64 rows of chunk c) ===============
    ThSm3* sm = (ThSm3*)smem;
    int m0 = ((int)blockIdx.x - nScan) * 64;
    int wid = tid >> 6, lane = tid & 63;
    int l15 = lane & 15, l4 = lane >> 4;
    int n0w = wid * 16;                      // wave's 16 hidden cols

    if (tid < 64) {
        int row = m0 + tid;
        const float* xp = &x[((size_t)t0h * 800 + row) * 6];
        float P = xp[0], E = xp[1], T1 = xp[2], T2 = xp[3];
        sm->xt[tid][0] = P;  sm->xt[tid][1] = E;     sm->xt[tid][2] = T1;
        sm->xt[tid][3] = T2; sm->xt[tid][4] = xp[4]; sm->xt[tid][5] = xp[5];
        float den = T2 - T1;
        float cf = (T1 + T2) / ((den == 0.0f) ? 1.0f : den);
        cf = fminf(fmaxf(cf, -0.999999f), 0.999999f);
        float vf = acosf(cf) * (1.0f / 3.1415f);
        vf = (T1 >= 0.0f) ? 0.0f : vf;
        vf = (T2 <= 0.0f) ? 1.0f : vf;
        sm->pls[tid] = P * (1.0f - vf);
        sm->evs[tid] = E;
        sm->psv[tid] = P * vf;
        PSw[row] = P * vf;
    }
    __syncthreads();   // B1: xt ready

    // ---- L1: thread = (k-octet jg, row-quad rg) -> swizzled Ah ----
    {
        int jg = tid & 31, rg = tid >> 5;
        int j0 = jg * 8;
        float4 wA[6], wB[6];
#pragma unroll
        for (int c = 0; c < 6; ++c) {
            wA[c] = *(const float4*)&w1T[c * 256 + j0];
            wB[c] = *(const float4*)&w1T[c * 256 + j0 + 4];
        }
#pragma unroll
        for (int rr = 0; rr < 4; ++rr) {
            int r = rg * 4 + rr;
            int srow = (m0 + r) % 800;
            const float* bp = &basec[(size_t)srow * 256 + j0];
            float4 b0 = *(const float4*)bp;
            float4 b1 = *(const float4*)(bp + 4);
            float a[8] = {b0.x, b0.y, b0.z, b0.w, b1.x, b1.y, b1.z, b1.w};
#pragma unroll
            for (int c = 0; c < 6; ++c) {
                float xv = sm->xt[r][c];
                a[0] = fmaf(xv, wA[c].x, a[0]);
                a[1] = fmaf(xv, wA[c].y, a[1]);
                a[2] = fmaf(xv, wA[c].z, a[2]);
                a[3] = fmaf(xv, wA[c].w, a[3]);
                a[4] = fmaf(xv, wB[c].x, a[4]);
                a[5] = fmaf(xv, wB[c].y, a[5]);
                a[6] = fmaf(xv, wB[c].z, a[6]);
                a[7] = fmaf(xv, wB[c].w, a[7]);
            }
            f16x8 hv;
#pragma unroll
            for (int e = 0; e < 8; ++e) hv[e] = (_Float16)tanh_fast(a[e]);
            sm->Ah[ah_swz(jg, r)] = hv;
        }
    }
    __syncthreads();   // B2: Ah ready

    // ---- GEMM: wave covers 64 rows (mf=4) x 16 hidden cols x 3 channels ----
    f32x4 acc[4][3];
#pragma unroll
    for (int ch = 0; ch < 3; ++ch) {
        float bb = b2[ch * 128 + n0w + l15];
#pragma unroll
        for (int mf = 0; mf < 4; ++mf) acc[mf][ch] = (f32x4){bb, bb, bb, bb};
    }
    f16x8 bf[3], bfn[3];
#pragma unroll
    for (int ch = 0; ch < 3; ++ch)
        bf[ch] = w2B[(size_t)l4 * 384 + ch * 128 + n0w + l15];
    for (int ks = 0; ks < 8; ++ks) {
        if (ks < 7) {
#pragma unroll
            for (int ch = 0; ch < 3; ++ch)
                bfn[ch] = w2B[(size_t)(ks + 1) * 1536 + l4 * 384 + ch * 128 + n0w + l15];
        }
        f16x8 af[4];
#pragma unroll
        for (int mf = 0; mf < 4; ++mf)
            af[mf] = sm->Ah[ah_swz(ks * 4 + l4, mf * 16 + l15)];
#pragma unroll
        for (int mf = 0; mf < 4; ++mf)
#pragma unroll
            for (int ch = 0; ch < 3; ++ch)
                acc[mf][ch] = __builtin_amdgcn_mfma_f32_16x16x32_f16(
                    af[mf], bf[ch], acc[mf][ch], 0, 0, 0);
        if (ks < 7) {
#pragma unroll
            for (int ch = 0; ch < 3; ++ch) bf[ch] = bfn[ch];
        }
    }

    // ---- epilogue: same-lane pl/ev/vm -> one packed uint2 store per cell ----
    int col = n0w + l15;
#pragma unroll
    for (int mf = 0; mf < 4; ++mf) {
#pragma unroll
        for (int rr = 0; rr < 4; ++rr) {
            int r = mf * 16 + l4 * 4 + rr;
            float vp = acc[mf][0][rr];
            float ve = acc[mf][1][rr];
            float vv = acc[mf][2][rr];
            float opl = sm->pls[r] * fminf(fmaxf(vp * (1.0f / 3.0f) + 0.5f, 0.0f), 1.0f);
            float oev = sm->evs[r] * fmaxf(ve, 0.0f) * 2.0f;
            float ovm = fminf(__expf(vv), 60000.0f);
            uint2 pv;
            pv.x = (unsigned)h_bits((_Float16)opl)
                 | ((unsigned)h_bits((_Float16)oev) << 16);
            pv.y = (unsigned)h_bits((_Float16)ovm);
            PVw[(size_t)(m0 + r) * 128 + col] = pv;
        }
    }
}

// ---------------------------------------------------------------------------
extern "C" void kernel_launch(void* const* d_in, const int* in_sizes, int n_in,
                              void* d_out, int out_size, void* d_ws, size_t ws_size,
                              hipStream_t stream)
{
    const float* x      = (const float*)d_in[0];
    const float* xc     = (const float*)d_in[1];
    const float* fcW1_w = (const float*)d_in[2];
    const float* fcW1_b = (const float*)d_in[3];
    const float* fcW2_w = (const float*)d_in[4];
    const float* fcW2_b = (const float*)d_in[5];
    const float* fcT1_w = (const float*)d_in[6];
    const float* fcT1_b = (const float*)d_in[7];
    const float* fcT2_w = (const float*)d_in[8];
    const float* fcT2_b = (const float*)d_in[9];
    const float* fcR1_w = (const float*)d_in[10];
    const float* fcR1_b = (const float*)d_in[11];
    const float* fcR2_w = (const float*)d_in[12];
    const float* fcR2_b = (const float*)d_in[13];
    float* out = (float*)d_out;

    char* wsb = (char*)d_ws;
    size_t off = 0;
    float* params = (float*)(wsb + off); off += (size_t)7 * NSH * 4;
    float* rbuf   = (float*)(wsb + off); off += (size_t)NRTAP * NSH * 4;
    float* basec  = (float*)(wsb + off); off += 800 * 256 * 4;
    float* h1w    = (float*)(wsb + off); off += 800 * 256 * 4;
    float* h1r    = (float*)(wsb + off); off += 800 * 256 * 4;
    float* state  = (float*)(wsb + off); off += (size_t)3 * NSH * 4;
    float* fut    = (float*)(wsb + off); off += (size_t)NRTAP * NSH * 4;
    _Float16* w2s = (_Float16*)(wsb + off); off += 98304 * 2;
    size_t fixedB = off;

    // per-timestep bytes in one chunk buffer: PV(8) per cell + PS row
    const size_t perT = (size_t)NSH * 8 + 800 * 4;
    long avail = (long)ws_size - (long)fixedB - 4096;
    int Tc = (int)(avail / (long)(2 * perT));
    if (Tc > 128) Tc = 128;
    Tc &= ~3;
    if (Tc < 4) Tc = 4;

    uint2* PV0 = (uint2*)(wsb + off); off += (size_t)Tc * NSH * 8;
    float* PS0 = (float*)(wsb + off); off += (size_t)Tc * 800 * 4;
    uint2* PV1 = (uint2*)(wsb + off); off += (size_t)Tc * NSH * 8;
    float* PS1 = (float*)(wsb + off); off += (size_t)Tc * 800 * 4;

    k_prep_w2h<<<384, 256, 0, stream>>>(fcT2_w, w2s);
    k_site_l1<<<800, 256, 0, stream>>>(xc, fcW1_w, fcW1_b, fcR1_w, fcR1_b,
                                       fcT1_w, fcT1_b, h1w, h1r, basec);
    k_whead<<<dim3(100, 7), 128, 0, stream>>>(h1w, fcW2_w, fcW2_b, params);
    k_softmax_ga<<<800, 128, 0, stream>>>(params + (size_t)6 * NSH);
    k_rhead<<<dim3(100, 15), 128, 0, stream>>>(h1r, fcR2_w, fcR2_b, rbuf);

    int nch = (NTIME + Tc - 1) / Tc;
    for (int c = 0; c <= nch; ++c) {
        int nScan = (c > 0) ? 200 : 0;
        int Tch = 0;
        if (c < nch) { Tch = NTIME - c * Tc; if (Tch > Tc) Tch = Tc; }
        int rowsH = Tch * 800;
        int thB = rowsH / 64;
        int grid = nScan + thB;
        if (grid == 0) continue;
        int t0s = (c - 1) * Tc;
        int Tcs = 0;
        if (c > 0) { Tcs = NTIME - t0s; if (Tcs > Tc) Tcs = Tc; }
        uint2* PVw = (c & 1) ? PV1 : PV0;
        float* PSw = (c & 1) ? PS1 : PS0;
        const uint2* PVr = ((c - 1) & 1) ? PV1 : PV0;
        const float* PSr = ((c - 1) & 1) ? PS1 : PS0;
        k_combo5<<<grid, 512, 0, stream>>>(
            x, fcT1_w, basec, (const f16x8*)w2s, fcT2_b, params, rbuf,
            state, fut, out,
            PVw, PSw, c * Tc, rowsH,
            PVr, PSr, t0s, Tcs, (c == 1) ? 1 : 0, nScan);
    }
}

// Round 13
// 458.586 us; speedup vs baseline: 1.0636x; 1.0636x over previous
//
#include <hip/hip_runtime.h>
#include <cmath>

// WaterNet: NH=128, NG=32, NR=15, NT=730, NS=800
#define NHID 128
#define NSITE 800
#define NTIME 730
#define NRTAP 15
constexpr int NSH = NSITE * NHID;  // 102400

typedef _Float16 f16x8 __attribute__((ext_vector_type(8)));
typedef _Float16 f16x2 __attribute__((ext_vector_type(2)));
typedef float f32x4 __attribute__((ext_vector_type(4)));

__device__ __forceinline__ float tanh_fast(float x) {
    float e = __expf(2.0f * x);
    return 1.0f - 2.0f / (e + 1.0f);
}
__device__ __forceinline__ float sigmoid_fast(float x) {
    return 1.0f / (1.0f + __expf(-x));
}
__device__ __forceinline__ unsigned short h_bits(_Float16 h) {
    union { _Float16 h; unsigned short u; } c; c.h = h; return c.u;
}
__device__ __forceinline__ void unpack_h2(unsigned u, float& a, float& b) {
    union { unsigned u; f16x2 h; } cv; cv.u = u;
    a = (float)cv.h.x; b = (float)cv.h.y;
}
// Swizzled index into 64-row A-fragment LDS tile: jg = k-octet (0..31), r = row (0..63).
// Conflict-free for L1 write and MFMA read (verified r7/r11: SQ_LDS_BANK_CONFLICT = 0).
__device__ __forceinline__ int ah_swz(int jg, int r) {
    return jg * 64 + ((r & ~7) | ((r ^ jg) & 7));
}

// ---------------------------------------------------------------------------
// P0: fcT2_w (fp32 [256][384]) -> fp16 MFMA layout w2s[K0][kg][col][e]
// ---------------------------------------------------------------------------
__global__ void k_prep_w2h(const float* __restrict__ w2, _Float16* __restrict__ w2s)
{
    int idx = blockIdx.x * 256 + threadIdx.x;
    if (idx >= 98304) return;
    int k = idx / 384, col = idx - k * 384;
    int K0 = k >> 5, kg = (k >> 3) & 3, e = k & 7;
    w2s[(size_t)K0 * 12288 + kg * 3072 + col * 8 + e] = (_Float16)w2[(size_t)k * 384 + col];
}

// ---------------------------------------------------------------------------
// A1: per-site layer-1 for all three heads.
// ---------------------------------------------------------------------------
__global__ void k_site_l1(const float* __restrict__ xc,
                          const float* __restrict__ w1W, const float* __restrict__ b1W,
                          const float* __restrict__ w1R, const float* __restrict__ b1R,
                          const float* __restrict__ w1T, const float* __restrict__ b1T,
                          float* __restrict__ h1w, float* __restrict__ h1r,
                          float* __restrict__ basec)
{
    __shared__ float xr[32];
    int s = blockIdx.x, j = threadIdx.x;
    if (j < 32) xr[j] = xc[s * 32 + j];
    __syncthreads();
    float aW = b1W[j], aR = b1R[j], aT = b1T[j];
#pragma unroll 8
    for (int k = 0; k < 32; ++k) {
        float xv = xr[k];
        aW = fmaf(xv, w1W[k * 256 + j], aW);
        aR = fmaf(xv, w1R[k * 256 + j], aR);
        aT = fmaf(xv, w1T[(6 + k) * 256 + j], aT);
    }
    h1w[s * 256 + j]   = tanh_fast(aW);
    h1r[s * 256 + j]   = tanh_fast(aR);
    basec[s * 256 + j] = aT;
}

// ---------------------------------------------------------------------------
// A2: static parameter head layer-2 + activations.
// ---------------------------------------------------------------------------
__global__ void k_whead(const float* __restrict__ h1w,
                        const float* __restrict__ w2, const float* __restrict__ b2,
                        float* __restrict__ params)
{
    __shared__ float h[8 * 256];
    int sBase = blockIdx.x * 8, g = blockIdx.y, tid = threadIdx.x;
    for (int p = tid; p < 2048; p += 128) h[p] = h1w[sBase * 256 + p];
    __syncthreads();
    float bias = b2[g * 128 + tid];
    float acc[8];
#pragma unroll
    for (int i = 0; i < 8; ++i) acc[i] = bias;
    for (int k = 0; k < 256; ++k) {
        float wv = w2[k * 896 + g * 128 + tid];
#pragma unroll
        for (int i = 0; i < 8; ++i) acc[i] = fmaf(h[i * 256 + k], wv, acc[i]);
    }
#pragma unroll
    for (int i = 0; i < 8; ++i) {
        float v = acc[i], o;
        if (g == 0 || g == 1 || g == 3)  o = sigmoid_fast(v);
        else if (g == 2)                 o = sigmoid_fast(v) * 0.1f;
        else if (g == 4)                 o = __expf(v) * 2.0f;
        else if (g == 5)                 o = fmaxf(v, 0.0f);
        else                             o = v;
        params[g * NSH + (sBase + i) * 128 + tid] = o;
    }
}

// ---------------------------------------------------------------------------
// A3: softmax of ga over 128 buckets, in place.
// ---------------------------------------------------------------------------
__global__ void k_softmax_ga(float* __restrict__ ga)
{
    int s = blockIdx.x, h = threadIdx.x;
    float v = ga[s * 128 + h];
    float m = v;
#pragma unroll
    for (int off = 32; off; off >>= 1) m = fmaxf(m, __shfl_xor(m, off));
    __shared__ float ra[2], rb[2];
    if ((h & 63) == 0) ra[h >> 6] = m;
    __syncthreads();
    m = fmaxf(ra[0], ra[1]);
    float e = __expf(v - m);
    float t = e;
#pragma unroll
    for (int off = 32; off; off >>= 1) t += __shfl_xor(t, off);
    if ((h & 63) == 0) rb[h >> 6] = t;
    __syncthreads();
    ga[s * 128 + h] = e / (rb[0] + rb[1]);
}

// ---------------------------------------------------------------------------
// A4: routing head layer-2, relu, [NRTAP][NSITE*NHID]
// ---------------------------------------------------------------------------
__global__ void k_rhead(const float* __restrict__ h1r,
                        const float* __restrict__ w2, const float* __restrict__ b2,
                        float* __restrict__ rbuf)
{
    __shared__ float h[8 * 256];
    int sBase = blockIdx.x * 8, g = blockIdx.y, tid = threadIdx.x;
    for (int p = tid; p < 2048; p += 128) h[p] = h1r[sBase * 256 + p];
    __syncthreads();
    int c = g * 128 + tid;
    float bias = b2[c];
    float acc[8];
#pragma unroll
    for (int i = 0; i < 8; ++i) acc[i] = bias;
    for (int k = 0; k < 256; ++k) {
        float wv = w2[k * 1920 + c];
#pragma unroll
        for (int i = 0; i < 8; ++i) acc[i] = fmaf(h[i * 256 + k], wv, acc[i]);
    }
    int hh = c / 15, ii = c - hh * 15;
#pragma unroll
    for (int i = 0; i < 8; ++i)
        rbuf[ii * NSH + (sBase + i) * 128 + hh] = fmaxf(acc[i], 0.0f);
}

// ---------------------------------------------------------------------------
// COMBO6: r12's structure with the 4-byte intermediate stream.
// Scan only needs (pl - ev), vm, ps:  H = relu(Ss + qf + delta).
// Timehead computes delta in-register (same-lane channels) -> one u32
// {delta:fp16 | vm:fp16} per cell. Halves stream bytes vs r12.
// ---------------------------------------------------------------------------
struct ThSm3 {
    f16x8 Ah[2048];                 // 32 KB swizzled A fragments (64 rows)
    float xt[64][6];
    float pls[64], evs[64], psv[64];
};                                  // 35,072 B

__global__ __launch_bounds__(512, 2) void k_combo6(
    const float* __restrict__ x, const float* __restrict__ w1T,
    const float* __restrict__ basec, const f16x8* __restrict__ w2B,
    const float* __restrict__ b2,
    const float* __restrict__ params, const float* __restrict__ rbuf,
    float* __restrict__ state, float* __restrict__ fut, float* __restrict__ out,
    unsigned* __restrict__ PVw, float* __restrict__ PSw, int t0h, int rowsH,
    const unsigned* __restrict__ PVr, const float* __restrict__ PSr,
    int t0s, int Tcs, int isFirst, int nScan)
{
    __shared__ __align__(16) char smem[sizeof(ThSm3)];
    int tid = threadIdx.x;

    if ((int)blockIdx.x < nScan) {
        // ===================== SCAN (chunk c-1), 4 sites =====================
        float* part = (float*)smem;                 // [8][128] = 4 KB
        int sl = tid >> 7, hc = tid & 127;
        int lane = tid & 63, wid = tid >> 6;
        int site = blockIdx.x * 4 + sl;
        int cell = site * 128 + hc;

        float kp  = params[0 * NSH + cell];
        float ksP = params[1 * NSH + cell];
        float kgP = params[2 * NSH + cell];
        float gp  = params[3 * NSH + cell];
        float gL  = params[4 * NSH + cell];
        float qb  = params[5 * NSH + cell];
        float ga  = params[6 * NSH + cell];
        float kq  = ksP * (1.0f - gp);

        float wr[NRTAP];
#pragma unroll
        for (int i = 0; i < NRTAP; ++i) wr[i] = ga * rbuf[i * NSH + cell];

        float Sf, Ss, Sg, f[NRTAP];
        if (isFirst) {
            Sf = Ss = Sg = 0.0f;
#pragma unroll
            for (int i = 0; i < NRTAP; ++i) f[i] = 0.0f;
        } else {
            Sf = state[cell];
            Ss = state[NSH + cell];
            Sg = state[2 * NSH + cell];
#pragma unroll
            for (int i = 0; i < NRTAP; ++i) f[i] = fut[i * NSH + cell];
        }

        const unsigned* pvp = PVr + cell;

#define LD_T(PV_, PS_, T_) { int t_ = (T_); bool ok_ = t_ < Tcs;               \
        PV_ = ok_ ? pvp[(size_t)t_ * NSH] : 0u;                                \
        PS_ = ok_ ? PSr[(size_t)t_ * 800 + site] : 0.0f; }

        unsigned pvA[4], pvB[4], pvC[4], pvD[4];
        float psA[4], psB[4], psC[4], psD[4];
#pragma unroll
        for (int i = 0; i < 4; ++i) LD_T(pvA[i], psA[i], i)
#pragma unroll
        for (int i = 0; i < 4; ++i) LD_T(pvB[i], psB[i], 4 + i)
#pragma unroll
        for (int i = 0; i < 4; ++i) LD_T(pvC[i], psC[i], 8 + i)
#pragma unroll
        for (int i = 0; i < 4; ++i) LD_T(pvD[i], psD[i], 12 + i)

        int ngroups = (Tcs + 3) >> 2;
        for (int g = 0; g < ngroups; ++g) {
            int tb = g * 4;
            unsigned pvE[4]; float psE[4];
#pragma unroll
            for (int i = 0; i < 4; ++i) LD_T(pvE[i], psE[i], tb + 16 + i)

            float cs[4];
#pragma unroll
            for (int i = 0; i < 4; ++i) {
                cs[i] = 0.0f;
                if (tb + i < Tcs) {
                    float dlt, vm;
                    unpack_h2(pvA[i], dlt, vm);
                    float ps = psA[i];

                    float x1 = Sf + ps;
                    float qf = fminf(x1, vm);
                    Sf = fmaxf(x1 - vm, 0.0f);
                    float H  = fmaxf(Ss + qf + dlt, 0.0f);
                    float qp = fmaxf(kp * (H - gL), 0.0f);
                    float mh = fminf(H, gL);
                    float qs = ksP * mh;
                    Ss = H - qp - qs;
                    float qg = fmaf(kgP, fmaf(qs, gp, Sg), qb);
                    Sg = Sg - qg;
                    float qt = qp + kq * mh + qg;
#pragma unroll
                    for (int j = 0; j < NRTAP; ++j) f[j] = fmaf(wr[j], qt, f[j]);
                    cs[i] = f[0];
#pragma unroll
                    for (int j = 0; j < NRTAP - 1; ++j) f[j] = f[j + 1];
                    f[NRTAP - 1] = 0.0f;
                }
            }
#pragma unroll
            for (int i = 0; i < 4; ++i) {
                float c = cs[i];
#pragma unroll
                for (int off = 32; off; off >>= 1) c += __shfl_xor(c, off);
                cs[i] = c;
            }
            if (lane == 0) {
#pragma unroll
                for (int i = 0; i < 4; ++i)
                    if (tb + i < Tcs) part[wid * 128 + tb + i] = cs[i];
            }
#pragma unroll
            for (int i = 0; i < 4; ++i) {
                pvA[i] = pvB[i]; pvB[i] = pvC[i]; pvC[i] = pvD[i]; pvD[i] = pvE[i];
                psA[i] = psB[i]; psB[i] = psC[i]; psC[i] = psD[i]; psD[i] = psE[i];
            }
        }
#undef LD_T

        state[cell]           = Sf;
        state[NSH + cell]     = Ss;
        state[2 * NSH + cell] = Sg;
#pragma unroll
        for (int i = 0; i < NRTAP; ++i) fut[i * NSH + cell] = f[i];

        __syncthreads();
        {
            int sl2 = tid >> 7, tl = tid & 127;
            for (int t = tl; t < Tcs; t += 128)
                out[(size_t)(t0s + t) * 800 + blockIdx.x * 4 + sl2] =
                    part[(sl2 * 2) * 128 + t] + part[(sl2 * 2 + 1) * 128 + t];
        }
        return;
    }

    // ===================== TIMEHEAD tile (64 rows of chunk c) ===============
    ThSm3* sm = (ThSm3*)smem;
    int m0 = ((int)blockIdx.x - nScan) * 64;
    int wid = tid >> 6, lane = tid & 63;
    int l15 = lane & 15, l4 = lane >> 4;
    int n0w = wid * 16;                      // wave's 16 hidden cols

    if (tid < 64) {
        int row = m0 + tid;
        const float* xp = &x[((size_t)t0h * 800 + row) * 6];
        float P = xp[0], E = xp[1], T1 = xp[2], T2 = xp[3];
        sm->xt[tid][0] = P;  sm->xt[tid][1] = E;     sm->xt[tid][2] = T1;
        sm->xt[tid][3] = T2; sm->xt[tid][4] = xp[4]; sm->xt[tid][5] = xp[5];
        float den = T2 - T1;
        float cf = (T1 + T2) / ((den == 0.0f) ? 1.0f : den);
        cf = fminf(fmaxf(cf, -0.999999f), 0.999999f);
        float vf = acosf(cf) * (1.0f / 3.1415f);
        vf = (T1 >= 0.0f) ? 0.0f : vf;
        vf = (T2 <= 0.0f) ? 1.0f : vf;
        sm->pls[tid] = P * (1.0f - vf);
        sm->evs[tid] = E;
        sm->psv[tid] = P * vf;
        PSw[row] = P * vf;
    }
    __syncthreads();   // B1: xt ready

    // ---- L1: thread = (k-octet jg, row-quad rg) -> swizzled Ah ----
    {
        int jg = tid & 31, rg = tid >> 5;
        int j0 = jg * 8;
        float4 wA[6], wB[6];
#pragma unroll
        for (int c = 0; c < 6; ++c) {
            wA[c] = *(const float4*)&w1T[c * 256 + j0];
            wB[c] = *(const float4*)&w1T[c * 256 + j0 + 4];
        }
#pragma unroll
        for (int rr = 0; rr < 4; ++rr) {
            int r = rg * 4 + rr;
            int srow = (m0 + r) % 800;
            const float* bp = &basec[(size_t)srow * 256 + j0];
            float4 b0 = *(const float4*)bp;
            float4 b1 = *(const float4*)(bp + 4);
            float a[8] = {b0.x, b0.y, b0.z, b0.w, b1.x, b1.y, b1.z, b1.w};
#pragma unroll
            for (int c = 0; c < 6; ++c) {
                float xv = sm->xt[r][c];
                a[0] = fmaf(xv, wA[c].x, a[0]);
                a[1] = fmaf(xv, wA[c].y, a[1]);
                a[2] = fmaf(xv, wA[c].z, a[2]);
                a[3] = fmaf(xv, wA[c].w, a[3]);
                a[4] = fmaf(xv, wB[c].x, a[4]);
                a[5] = fmaf(xv, wB[c].y, a[5]);
                a[6] = fmaf(xv, wB[c].z, a[6]);
                a[7] = fmaf(xv, wB[c].w, a[7]);
            }
            f16x8 hv;
#pragma unroll
            for (int e = 0; e < 8; ++e) hv[e] = (_Float16)tanh_fast(a[e]);
            sm->Ah[ah_swz(jg, r)] = hv;
        }
    }
    __syncthreads();   // B2: Ah ready

    // ---- GEMM: wave covers 64 rows (mf=4) x 16 hidden cols x 3 channels ----
    f32x4 acc[4][3];
#pragma unroll
    for (int ch = 0; ch < 3; ++ch) {
        float bb = b2[ch * 128 + n0w + l15];
#pragma unroll
        for (int mf = 0; mf < 4; ++mf) acc[mf][ch] = (f32x4){bb, bb, bb, bb};
    }
    f16x8 bf[3], bfn[3];
#pragma unroll
    for (int ch = 0; ch < 3; ++ch)
        bf[ch] = w2B[(size_t)l4 * 384 + ch * 128 + n0w + l15];
    for (int ks = 0; ks < 8; ++ks) {
        if (ks < 7) {
#pragma unroll
            for (int ch = 0; ch < 3; ++ch)
                bfn[ch] = w2B[(size_t)(ks + 1) * 1536 + l4 * 384 + ch * 128 + n0w + l15];
        }
        f16x8 af[4];
#pragma unroll
        for (int mf = 0; mf < 4; ++mf)
            af[mf] = sm->Ah[ah_swz(ks * 4 + l4, mf * 16 + l15)];
#pragma unroll
        for (int mf = 0; mf < 4; ++mf)
#pragma unroll
            for (int ch = 0; ch < 3; ++ch)
                acc[mf][ch] = __builtin_amdgcn_mfma_f32_16x16x32_f16(
                    af[mf], bf[ch], acc[mf][ch], 0, 0, 0);
        if (ks < 7) {
#pragma unroll
            for (int ch = 0; ch < 3; ++ch) bf[ch] = bfn[ch];
        }
    }

    // ---- epilogue: same-lane pl/ev/vm -> one packed u32 {delta, vm}/cell ----
    int col = n0w + l15;
#pragma unroll
    for (int mf = 0; mf < 4; ++mf) {
#pragma unroll
        for (int rr = 0; rr < 4; ++rr) {
            int r = mf * 16 + l4 * 4 + rr;
            float vp = acc[mf][0][rr];
            float ve = acc[mf][1][rr];
            float vv = acc[mf][2][rr];
            float opl = sm->pls[r] * fminf(fmaxf(vp * (1.0f / 3.0f) + 0.5f, 0.0f), 1.0f);
            float oev = sm->evs[r] * fmaxf(ve, 0.0f) * 2.0f;
            float dlt = opl - oev;
            float ovm = fminf(__expf(vv), 60000.0f);
            unsigned pv = (unsigned)h_bits((_Float16)dlt)
                        | ((unsigned)h_bits((_Float16)ovm) << 16);
            PVw[(size_t)(m0 + r) * 128 + col] = pv;
        }
    }
}

// ---------------------------------------------------------------------------
extern "C" void kernel_launch(void* const* d_in, const int* in_sizes, int n_in,
                              void* d_out, int out_size, void* d_ws, size_t ws_size,
                              hipStream_t stream)
{
    const float* x      = (const float*)d_in[0];
    const float* xc     = (const float*)d_in[1];
    const float* fcW1_w = (const float*)d_in[2];
    const float* fcW1_b = (const float*)d_in[3];
    const float* fcW2_w = (const float*)d_in[4];
    const float* fcW2_b = (const float*)d_in[5];
    const float* fcT1_w = (const float*)d_in[6];
    const float* fcT1_b = (const float*)d_in[7];
    const float* fcT2_w = (const float*)d_in[8];
    const float* fcT2_b = (const float*)d_in[9];
    const float* fcR1_w = (const float*)d_in[10];
    const float* fcR1_b = (const float*)d_in[11];
    const float* fcR2_w = (const float*)d_in[12];
    const float* fcR2_b = (const float*)d_in[13];
    float* out = (float*)d_out;

    char* wsb = (char*)d_ws;
    size_t off = 0;
    float* params = (float*)(wsb + off); off += (size_t)7 * NSH * 4;
    float* rbuf   = (float*)(wsb + off); off += (size_t)NRTAP * NSH * 4;
    float* basec  = (float*)(wsb + off); off += 800 * 256 * 4;
    float* h1w    = (float*)(wsb + off); off += 800 * 256 * 4;
    float* h1r    = (float*)(wsb + off); off += 800 * 256 * 4;
    float* state  = (float*)(wsb + off); off += (size_t)3 * NSH * 4;
    float* fut    = (float*)(wsb + off); off += (size_t)NRTAP * NSH * 4;
    _Float16* w2s = (_Float16*)(wsb + off); off += 98304 * 2;
    size_t fixedB = off;

    // per-timestep bytes in one chunk buffer: PV(4) per cell + PS row
    const size_t perT = (size_t)NSH * 4 + 800 * 4;
    long avail = (long)ws_size - (long)fixedB - 4096;
    int Tc = (int)(avail / (long)(2 * perT));
    if (Tc > 128) Tc = 128;
    Tc &= ~3;
    if (Tc < 4) Tc = 4;

    unsigned* PV0 = (unsigned*)(wsb + off); off += (size_t)Tc * NSH * 4;
    float*    PS0 = (float*)(wsb + off);    off += (size_t)Tc * 800 * 4;
    unsigned* PV1 = (unsigned*)(wsb + off); off += (size_t)Tc * NSH * 4;
    float*    PS1 = (float*)(wsb + off);    off += (size_t)Tc * 800 * 4;

    k_prep_w2h<<<384, 256, 0, stream>>>(fcT2_w, w2s);
    k_site_l1<<<800, 256, 0, stream>>>(xc, fcW1_w, fcW1_b, fcR1_w, fcR1_b,
                                       fcT1_w, fcT1_b, h1w, h1r, basec);
    k_whead<<<dim3(100, 7), 128, 0, stream>>>(h1w, fcW2_w, fcW2_b, params);
    k_softmax_ga<<<800, 128, 0, stream>>>(params + (size_t)6 * NSH);
    k_rhead<<<dim3(100, 15), 128, 0, stream>>>(h1r, fcR2_w, fcR2_b, rbuf);

    int nch = (NTIME + Tc - 1) / Tc;
    for (int c = 0; c <= nch; ++c) {
        int nScan = (c > 0) ? 200 : 0;
        int Tch = 0;
        if (c < nch) { Tch = NTIME - c * Tc; if (Tch > Tc) Tch = Tc; }
        int rowsH = Tch * 800;
        int thB = rowsH / 64;
        int grid = nScan + thB;
        if (grid == 0) continue;
        int t0s = (c - 1) * Tc;
        int Tcs = 0;
        if (c > 0) { Tcs = NTIME - t0s; if (Tcs > Tc) Tcs = Tc; }
        unsigned* PVw = (c & 1) ? PV1 : PV0;
        float*    PSw = (c & 1) ? PS1 : PS0;
        const unsigned* PVr = ((c - 1) & 1) ? PV1 : PV0;
        const float*    PSr = ((c - 1) & 1) ? PS1 : PS0;
        k_combo6<<<grid, 512, 0, stream>>>(
            x, fcT1_w, basec, (const f16x8*)w2s, fcT2_b, params, rbuf,
            state, fut, out,
            PVw, PSw, c * Tc, rowsH,
            PVr, PSr, t0s, Tcs, (c == 1) ? 1 : 0, nScan);
    }
}

// Round 15
// 423.329 us; speedup vs baseline: 1.1522x; 1.0833x over previous
//
#include <hip/hip_runtime.h>
#include <cmath>

// WaterNet: NH=128, NG=32, NR=15, NT=730, NS=800
#define NHID 128
#define NSITE 800
#define NTIME 730
#define NRTAP 15
#define NCH 7
#define TCMAX 128
#define TPAD 24
constexpr int NSH = NSITE * NHID;  // 102400

typedef _Float16 f16x8 __attribute__((ext_vector_type(8)));
typedef _Float16 f16x2 __attribute__((ext_vector_type(2)));
typedef float f32x4 __attribute__((ext_vector_type(4)));

__device__ __forceinline__ float tanh_fast(float x) {
    float e = __expf(2.0f * x);
    return 1.0f - 2.0f / (e + 1.0f);
}
__device__ __forceinline__ float sigmoid_fast(float x) {
    return 1.0f / (1.0f + __expf(-x));
}
__device__ __forceinline__ unsigned short h_bits(_Float16 h) {
    union { _Float16 h; unsigned short u; } c; c.h = h; return c.u;
}
__device__ __forceinline__ void unpack_h2(unsigned u, float& a, float& b) {
    union { unsigned u; f16x2 h; } cv; cv.u = u;
    a = (float)cv.h.x; b = (float)cv.h.y;
}
// Swizzled index into 64-row A-fragment LDS tile (verified 0 conflicts r7/r11).
__device__ __forceinline__ int ah_swz(int jg, int r) {
    return jg * 64 + ((r & ~7) | ((r ^ jg) & 7));
}

// ---------------------------------------------------------------------------
// P0: fcT2_w (fp32 [256][384]) -> fp16 MFMA layout w2s[K0][kg][col][e]
// ---------------------------------------------------------------------------
__global__ void k_prep_w2h(const float* __restrict__ w2, _Float16* __restrict__ w2s)
{
    int idx = blockIdx.x * 256 + threadIdx.x;
    if (idx >= 98304) return;
    int k = idx / 384, col = idx - k * 384;
    int K0 = k >> 5, kg = (k >> 3) & 3, e = k & 7;
    w2s[(size_t)K0 * 12288 + kg * 3072 + col * 8 + e] = (_Float16)w2[(size_t)k * 384 + col];
}

// ---------------------------------------------------------------------------
// A1: per-site layer-1 for all three heads.
// ---------------------------------------------------------------------------
__global__ void k_site_l1(const float* __restrict__ xc,
                          const float* __restrict__ w1W, const float* __restrict__ b1W,
                          const float* __restrict__ w1R, const float* __restrict__ b1R,
                          const float* __restrict__ w1T, const float* __restrict__ b1T,
                          float* __restrict__ h1w, float* __restrict__ h1r,
                          float* __restrict__ basec)
{
    __shared__ float xr[32];
    int s = blockIdx.x, j = threadIdx.x;
    if (j < 32) xr[j] = xc[s * 32 + j];
    __syncthreads();
    float aW = b1W[j], aR = b1R[j], aT = b1T[j];
#pragma unroll 8
    for (int k = 0; k < 32; ++k) {
        float xv = xr[k];
        aW = fmaf(xv, w1W[k * 256 + j], aW);
        aR = fmaf(xv, w1R[k * 256 + j], aR);
        aT = fmaf(xv, w1T[(6 + k) * 256 + j], aT);
    }
    h1w[s * 256 + j]   = tanh_fast(aW);
    h1r[s * 256 + j]   = tanh_fast(aR);
    basec[s * 256 + j] = aT;
}

// ---------------------------------------------------------------------------
// COMBO7 block ranges:
//   [0, nScan)                 : scan of chunk c-1 (4 sites/block)
//   [nScan, +nWh)              : whead units (c==0 only), softmax folded in
//   [nScan+nWh, +nRh)          : rhead units (c==0 only)
//   [nScan+nWh+nRh, ...)       : timehead 64-row tiles of chunk c
// ---------------------------------------------------------------------------
struct ThSm3 {
    f16x8 Ah[2048];                 // 32 KB swizzled A fragments (64 rows)
    float xt[64][6];
    float pls[64], evs[64], psv[64];
};                                  // 35,072 B

__global__ __launch_bounds__(512, 2) void k_combo7(
    const float* __restrict__ x, const float* __restrict__ w1T,
    const float* __restrict__ basec, const f16x8* __restrict__ w2B,
    const float* __restrict__ b2,
    float* __restrict__ params, float* __restrict__ rbuf,
    float* __restrict__ state, float* __restrict__ fut, float* __restrict__ out,
    unsigned* __restrict__ PVw, float* __restrict__ PSw, int t0h, int rowsH,
    const unsigned* __restrict__ PVr, const float* __restrict__ PSr,
    int t0s, int Tcs, int isFirst, int nScan, int nWh, int nRh,
    const float* __restrict__ h1w, const float* __restrict__ h1r,
    const float* __restrict__ w2W, const float* __restrict__ b2W,
    const float* __restrict__ w2R, const float* __restrict__ b2R)
{
    __shared__ __align__(16) char smem[sizeof(ThSm3)];
    int tid = threadIdx.x;
    int bid = (int)blockIdx.x;

    if (bid < nScan) {
        // ===================== SCAN (chunk c-1), 4 sites =====================
        __builtin_amdgcn_s_setprio(1);   // scan is the dispatch critical path
        float* part = (float*)smem;                 // [8][128] = 4 KB
        int sl = tid >> 7, hc = tid & 127;
        int lane = tid & 63, wid = tid >> 6;
        int site = bid * 4 + sl;
        int cell = site * 128 + hc;

        float kp  = params[0 * NSH + cell];
        float ksP = params[1 * NSH + cell];
        float kgP = params[2 * NSH + cell];
        float gp  = params[3 * NSH + cell];
        float gL  = params[4 * NSH + cell];
        float qb  = params[5 * NSH + cell];
        float ga  = params[6 * NSH + cell];
        float kq  = ksP * (1.0f - gp);

        float wr[NRTAP];
#pragma unroll
        for (int i = 0; i < NRTAP; ++i) wr[i] = ga * rbuf[i * NSH + cell];

        float Sf, Ss, Sg, f[NRTAP];
        if (isFirst) {
            Sf = Ss = Sg = 0.0f;
#pragma unroll
            for (int i = 0; i < NRTAP; ++i) f[i] = 0.0f;
        } else {
            Sf = state[cell];
            Ss = state[NSH + cell];
            Sg = state[2 * NSH + cell];
#pragma unroll
            for (int i = 0; i < NRTAP; ++i) f[i] = fut[i * NSH + cell];
        }

        const unsigned* pvp = PVr + cell;

        // loads are UNGUARDED: buffers padded by TPAD steps; compute is guarded
#define LD_T(PV_, PS_, T_) { int t_ = (T_);                                    \
        PV_ = pvp[(size_t)t_ * NSH];                                           \
        PS_ = PSr[(size_t)t_ * 800 + site]; }

        unsigned pvA[4], pvB[4], pvC[4], pvD[4];
        float psA[4], psB[4], psC[4], psD[4];
#pragma unroll
        for (int i = 0; i < 4; ++i) LD_T(pvA[i], psA[i], i)
#pragma unroll
        for (int i = 0; i < 4; ++i) LD_T(pvB[i], psB[i], 4 + i)
#pragma unroll
        for (int i = 0; i < 4; ++i) LD_T(pvC[i], psC[i], 8 + i)
#pragma unroll
        for (int i = 0; i < 4; ++i) LD_T(pvD[i], psD[i], 12 + i)

        int ngroups = (Tcs + 3) >> 2;
        for (int g = 0; g < ngroups; ++g) {
            int tb = g * 4;
            unsigned pvE[4]; float psE[4];
#pragma unroll
            for (int i = 0; i < 4; ++i) LD_T(pvE[i], psE[i], tb + 16 + i)

            float cs[4];
#pragma unroll
            for (int i = 0; i < 4; ++i) {
                cs[i] = 0.0f;
                if (tb + i < Tcs) {
                    float dlt, vm;
                    unpack_h2(pvA[i], dlt, vm);
                    float ps = psA[i];

                    float x1 = Sf + ps;
                    float qf = fminf(x1, vm);
                    Sf = fmaxf(x1 - vm, 0.0f);
                    float H  = fmaxf(Ss + qf + dlt, 0.0f);
                    float qp = fmaxf(kp * (H - gL), 0.0f);
                    float mh = fminf(H, gL);
                    float qs = ksP * mh;
                    Ss = H - qp - qs;
                    float qg = fmaf(kgP, fmaf(qs, gp, Sg), qb);
                    Sg = Sg - qg;
                    float qt = qp + kq * mh + qg;
#pragma unroll
                    for (int j = 0; j < NRTAP; ++j) f[j] = fmaf(wr[j], qt, f[j]);
                    cs[i] = f[0];
#pragma unroll
                    for (int j = 0; j < NRTAP - 1; ++j) f[j] = f[j + 1];
                    f[NRTAP - 1] = 0.0f;
                }
            }
#pragma unroll
            for (int i = 0; i < 4; ++i) {
                float c = cs[i];
#pragma unroll
                for (int off = 32; off; off >>= 1) c += __shfl_xor(c, off);
                cs[i] = c;
            }
            if (lane == 0) {
#pragma unroll
                for (int i = 0; i < 4; ++i)
                    if (tb + i < Tcs) part[wid * 128 + tb + i] = cs[i];
            }
#pragma unroll
            for (int i = 0; i < 4; ++i) {
                pvA[i] = pvB[i]; pvB[i] = pvC[i]; pvC[i] = pvD[i]; pvD[i] = pvE[i];
                psA[i] = psB[i]; psB[i] = psC[i]; psC[i] = psD[i]; psD[i] = psE[i];
            }
        }
#undef LD_T
        __builtin_amdgcn_s_setprio(0);

        state[cell]           = Sf;
        state[NSH + cell]     = Ss;
        state[2 * NSH + cell] = Sg;
#pragma unroll
        for (int i = 0; i < NRTAP; ++i) fut[i * NSH + cell] = f[i];

        __syncthreads();
        {
            int sl2 = tid >> 7, tl = tid & 127;
            for (int t = tl; t < Tcs; t += 128)
                out[(size_t)(t0s + t) * 800 + bid * 4 + sl2] =
                    part[(sl2 * 2) * 128 + t] + part[(sl2 * 2 + 1) * 128 + t];
        }
        return;
    }

    if (bid < nScan + nWh) {
        // ========== WHEAD: static param head layer-2 (+softmax for ga) ======
        int bidh = bid - nScan;              // 0..174
        int ublk = tid >> 7, utid = tid & 127;
        int g = bidh / 25;                   // uniform per block
        int sBase = ((bidh % 25) * 4 + ublk) * 8;
        float* hb  = (float*)smem + ublk * 2048;
        float* red = (float*)smem + 8192;    // [8 waves][8]

        for (int p = utid; p < 2048; p += 128) hb[p] = h1w[sBase * 256 + p];
        __syncthreads();

        float bias = b2W[g * 128 + utid];
        float acc[8];
#pragma unroll
        for (int i = 0; i < 8; ++i) acc[i] = bias;
        for (int k = 0; k < 256; ++k) {
            float wv = w2W[k * 896 + g * 128 + utid];
#pragma unroll
            for (int i = 0; i < 8; ++i) acc[i] = fmaf(hb[i * 256 + k], wv, acc[i]);
        }
        if (g != 6) {
#pragma unroll
            for (int i = 0; i < 8; ++i) {
                float v = acc[i], o;
                if (g == 0 || g == 1 || g == 3)  o = sigmoid_fast(v);
                else if (g == 2)                 o = sigmoid_fast(v) * 0.1f;
                else if (g == 4)                 o = __expf(v) * 2.0f;
                else                             o = fmaxf(v, 0.0f);
                params[g * NSH + (sBase + i) * 128 + utid] = o;
            }
        } else {
            // softmax over the 128 buckets (utid axis), per site i
            int w2i = ublk * 2 + (utid >> 6);
            float m[8];
#pragma unroll
            for (int i = 0; i < 8; ++i) m[i] = acc[i];
#pragma unroll
            for (int off = 32; off; off >>= 1)
#pragma unroll
                for (int i = 0; i < 8; ++i) m[i] = fmaxf(m[i], __shfl_xor(m[i], off));
            if ((utid & 63) == 0) {
#pragma unroll
                for (int i = 0; i < 8; ++i) red[w2i * 8 + i] = m[i];
            }
            __syncthreads();
#pragma unroll
            for (int i = 0; i < 8; ++i)
                m[i] = fmaxf(red[(ublk * 2) * 8 + i], red[(ublk * 2 + 1) * 8 + i]);
            float e[8], sm_[8];
#pragma unroll
            for (int i = 0; i < 8; ++i) { e[i] = __expf(acc[i] - m[i]); sm_[i] = e[i]; }
#pragma unroll
            for (int off = 32; off; off >>= 1)
#pragma unroll
                for (int i = 0; i < 8; ++i) sm_[i] += __shfl_xor(sm_[i], off);
            __syncthreads();   // WAR on red
            if ((utid & 63) == 0) {
#pragma unroll
                for (int i = 0; i < 8; ++i) red[w2i * 8 + i] = sm_[i];
            }
            __syncthreads();
#pragma unroll
            for (int i = 0; i < 8; ++i) {
                float tot = red[(ublk * 2) * 8 + i] + red[(ublk * 2 + 1) * 8 + i];
                params[6 * NSH + (sBase + i) * 128 + utid] = e[i] / tot;
            }
        }
        return;
    }

    if (bid < nScan + nWh + nRh) {
        // ========== RHEAD: routing head layer-2, relu ==========
        int bidr = bid - nScan - nWh;        // 0..374
        int ublk = tid >> 7, utid = tid & 127;
        int unit = bidr * 4 + ublk;          // 0..1499
        int g2 = unit % 15;
        int sBase = (unit / 15) * 8;
        float* hb = (float*)smem + ublk * 2048;

        for (int p = utid; p < 2048; p += 128) hb[p] = h1r[sBase * 256 + p];
        __syncthreads();

        int c2 = g2 * 128 + utid;
        float bias = b2R[c2];
        float acc[8];
#pragma unroll
        for (int i = 0; i < 8; ++i) acc[i] = bias;
        for (int k = 0; k < 256; ++k) {
            float wv = w2R[k * 1920 + c2];
#pragma unroll
            for (int i = 0; i < 8; ++i) acc[i] = fmaf(hb[i * 256 + k], wv, acc[i]);
        }
        int hh = c2 / 15, ii = c2 - hh * 15;
#pragma unroll
        for (int i = 0; i < 8; ++i)
            rbuf[ii * NSH + (sBase + i) * 128 + hh] = fmaxf(acc[i], 0.0f);
        return;
    }

    // ===================== TIMEHEAD tile (64 rows of chunk c) ===============
    ThSm3* sm = (ThSm3*)smem;
    int m0 = (bid - nScan - nWh - nRh) * 64;
    if (m0 >= rowsH) return;
    int wid = tid >> 6, lane = tid & 63;
    int l15 = lane & 15, l4 = lane >> 4;
    int n0w = wid * 16;                      // wave's 16 hidden cols

    if (tid < 64) {
        int row = m0 + tid;
        const float* xp = &x[((size_t)t0h * 800 + row) * 6];
        float P = xp[0], E = xp[1], T1 = xp[2], T2 = xp[3];
        sm->xt[tid][0] = P;  sm->xt[tid][1] = E;     sm->xt[tid][2] = T1;
        sm->xt[tid][3] = T2; sm->xt[tid][4] = xp[4]; sm->xt[tid][5] = xp[5];
        float den = T2 - T1;
        float cf = (T1 + T2) / ((den == 0.0f) ? 1.0f : den);
        cf = fminf(fmaxf(cf, -0.999999f), 0.999999f);
        float vf = acosf(cf) * (1.0f / 3.1415f);
        vf = (T1 >= 0.0f) ? 0.0f : vf;
        vf = (T2 <= 0.0f) ? 1.0f : vf;
        sm->pls[tid] = P * (1.0f - vf);
        sm->evs[tid] = E;
        sm->psv[tid] = P * vf;
        PSw[row] = P * vf;
    }
    __syncthreads();   // B1: xt ready

    // ---- L1: thread = (k-octet jg, row-quad rg) -> swizzled Ah ----
    {
        int jg = tid & 31, rg = tid >> 5;
        int j0 = jg * 8;
        float4 wA[6], wB[6];
#pragma unroll
        for (int c = 0; c < 6; ++c) {
            wA[c] = *(const float4*)&w1T[c * 256 + j0];
            wB[c] = *(const float4*)&w1T[c * 256 + j0 + 4];
        }
#pragma unroll
        for (int rr = 0; rr < 4; ++rr) {
            int r = rg * 4 + rr;
            int srow = (m0 + r) % 800;
            const float* bp = &basec[(size_t)srow * 256 + j0];
            float4 b0 = *(const float4*)bp;
            float4 b1 = *(const float4*)(bp + 4);
            float a[8] = {b0.x, b0.y, b0.z, b0.w, b1.x, b1.y, b1.z, b1.w};
#pragma unroll
            for (int c = 0; c < 6; ++c) {
                float xv = sm->xt[r][c];
                a[0] = fmaf(xv, wA[c].x, a[0]);
                a[1] = fmaf(xv, wA[c].y, a[1]);
                a[2] = fmaf(xv, wA[c].z, a[2]);
                a[3] = fmaf(xv, wA[c].w, a[3]);
                a[4] = fmaf(xv, wB[c].x, a[4]);
                a[5] = fmaf(xv, wB[c].y, a[5]);
                a[6] = fmaf(xv, wB[c].z, a[6]);
                a[7] = fmaf(xv, wB[c].w, a[7]);
            }
            f16x8 hv;
#pragma unroll
            for (int e = 0; e < 8; ++e) hv[e] = (_Float16)tanh_fast(a[e]);
            sm->Ah[ah_swz(jg, r)] = hv;
        }
    }
    __syncthreads();   // B2: Ah ready

    // ---- GEMM: wave covers 64 rows (mf=4) x 16 hidden cols x 3 channels ----
    f32x4 acc[4][3];
#pragma unroll
    for (int ch = 0; ch < 3; ++ch) {
        float bb = b2[ch * 128 + n0w + l15];
#pragma unroll
        for (int mf = 0; mf < 4; ++mf) acc[mf][ch] = (f32x4){bb, bb, bb, bb};
    }
    f16x8 bf[3], bfn[3];
#pragma unroll
    for (int ch = 0; ch < 3; ++ch)
        bf[ch] = w2B[(size_t)l4 * 384 + ch * 128 + n0w + l15];
    for (int ks = 0; ks < 8; ++ks) {
        if (ks < 7) {
#pragma unroll
            for (int ch = 0; ch < 3; ++ch)
                bfn[ch] = w2B[(size_t)(ks + 1) * 1536 + l4 * 384 + ch * 128 + n0w + l15];
        }
        f16x8 af[4];
#pragma unroll
        for (int mf = 0; mf < 4; ++mf)
            af[mf] = sm->Ah[ah_swz(ks * 4 + l4, mf * 16 + l15)];
#pragma unroll
        for (int mf = 0; mf < 4; ++mf)
#pragma unroll
            for (int ch = 0; ch < 3; ++ch)
                acc[mf][ch] = __builtin_amdgcn_mfma_f32_16x16x32_f16(
                    af[mf], bf[ch], acc[mf][ch], 0, 0, 0);
        if (ks < 7) {
#pragma unroll
            for (int ch = 0; ch < 3; ++ch) bf[ch] = bfn[ch];
        }
    }

    // ---- epilogue: same-lane pl/ev/vm -> one packed u32 {delta, vm}/cell ----
    int col = n0w + l15;
#pragma unroll
    for (int mf = 0; mf < 4; ++mf) {
#pragma unroll
        for (int rr = 0; rr < 4; ++rr) {
            int r = mf * 16 + l4 * 4 + rr;
            float vp = acc[mf][0][rr];
            float ve = acc[mf][1][rr];
            float vv = acc[mf][2][rr];
            float opl = sm->pls[r] * fminf(fmaxf(vp * (1.0f / 3.0f) + 0.5f, 0.0f), 1.0f);
            float oev = sm->evs[r] * fmaxf(ve, 0.0f) * 2.0f;
            float dlt = opl - oev;
            float ovm = fminf(__expf(vv), 60000.0f);
            unsigned pv = (unsigned)h_bits((_Float16)dlt)
                        | ((unsigned)h_bits((_Float16)ovm) << 16);
            PVw[(size_t)(m0 + r) * 128 + col] = pv;
        }
    }
}

// ---------------------------------------------------------------------------
extern "C" void kernel_launch(void* const* d_in, const int* in_sizes, int n_in,
                              void* d_out, int out_size, void* d_ws, size_t ws_size,
                              hipStream_t stream)
{
    const float* x      = (const float*)d_in[0];
    const float* xc     = (const float*)d_in[1];
    const float* fcW1_w = (const float*)d_in[2];
    const float* fcW1_b = (const float*)d_in[3];
    const float* fcW2_w = (const float*)d_in[4];
    const float* fcW2_b = (const float*)d_in[5];
    const float* fcT1_w = (const float*)d_in[6];
    const float* fcT1_b = (const float*)d_in[7];
    const float* fcT2_w = (const float*)d_in[8];
    const float* fcT2_b = (const float*)d_in[9];
    const float* fcR1_w = (const float*)d_in[10];
    const float* fcR1_b = (const float*)d_in[11];
    const float* fcR2_w = (const float*)d_in[12];
    const float* fcR2_b = (const float*)d_in[13];
    float* out = (float*)d_out;

    char* wsb = (char*)d_ws;
    size_t off = 0;
    float* params = (float*)(wsb + off); off += (size_t)7 * NSH * 4;
    float* rbuf   = (float*)(wsb + off); off += (size_t)NRTAP * NSH * 4;
    float* basec  = (float*)(wsb + off); off += 800 * 256 * 4;
    float* h1w    = (float*)(wsb + off); off += 800 * 256 * 4;
    float* h1r    = (float*)(wsb + off); off += 800 * 256 * 4;
    float* state  = (float*)(wsb + off); off += (size_t)3 * NSH * 4;
    float* fut    = (float*)(wsb + off); off += (size_t)NRTAP * NSH * 4;
    _Float16* w2s = (_Float16*)(wsb + off); off += 98304 * 2;

    // ping-pong chunk buffers, padded by TPAD steps for unguarded prefetch
    const int TBUF = TCMAX + TPAD;
    unsigned* PV0 = (unsigned*)(wsb + off); off += (size_t)TBUF * NSH * 4;
    float*    PS0 = (float*)(wsb + off);    off += (size_t)TBUF * 800 * 4;
    unsigned* PV1 = (unsigned*)(wsb + off); off += (size_t)TBUF * NSH * 4;
    float*    PS1 = (float*)(wsb + off);    off += (size_t)TBUF * 800 * 4;

    // chunk schedule: small tail -> tiny exposed final scan
    const int csz[NCH]   = {128, 128, 128, 128, 128, 72, 18};
    int cstart[NCH];
    { int a = 0; for (int i = 0; i < NCH; ++i) { cstart[i] = a; a += csz[i]; } }

    k_prep_w2h<<<384, 256, 0, stream>>>(fcT2_w, w2s);
    k_site_l1<<<800, 256, 0, stream>>>(xc, fcW1_w, fcW1_b, fcR1_w, fcR1_b,
                                       fcT1_w, fcT1_b, h1w, h1r, basec);

    for (int c = 0; c <= NCH; ++c) {
        int nScan = (c > 0) ? 200 : 0;
        int nWh   = (c == 0) ? 175 : 0;
        int nRh   = (c == 0) ? 375 : 0;
        int Tch = (c < NCH) ? csz[c] : 0;
        int rowsH = Tch * 800;
        int thB = rowsH / 64;
        int grid = nScan + nWh + nRh + thB;
        if (grid == 0) continue;
        int t0h = (c < NCH) ? cstart[c] : 0;
        int t0s = (c > 0) ? cstart[c - 1] : 0;
        int Tcs = (c > 0) ? csz[c - 1] : 0;
        unsigned* PVw = (c & 1) ? PV1 : PV0;
        float*    PSw = (c & 1) ? PS1 : PS0;
        const unsigned* PVr = ((c - 1) & 1) ? PV1 : PV0;
        const float*    PSr = ((c - 1) & 1) ? PS1 : PS0;
        k_combo7<<<grid, 512, 0, stream>>>(
            x, fcT1_w, basec, (const f16x8*)w2s, fcT2_b, params, rbuf,
            state, fut, out,
            PVw, PSw, t0h, rowsH,
            PVr, PSr, t0s, Tcs, (c == 1) ? 1 : 0, nScan, nWh, nRh,
            h1w, h1r, fcW2_w, fcW2_b, fcR2_w, fcR2_b);
    }
}